// Round 1
// baseline (1187.487 us; speedup 1.0000x reference)
//
#include <hip/hip_runtime.h>
#include <math.h>

#define DMODEL 1024
#define NHEADS 16
#define DKH    64
#define SEQ    1024
#define BATCH  4
#define NREL   33
#define MROWS  (BATCH*SEQ)   // 4096

// ---------------------------------------------------------------------------
// Y = X @ W^T + bias.  X: [4096,1024] row-major, W: [1024,1024] row-major
// (out-feature major, so rows of W are contiguous dot vectors).
// MODE 0: scatter output into [B,H,S,dk] head-split layout (q/k/v workspace)
// MODE 1: write [B,S,D] row-major (final output)
// 64x64 tile, 256 threads, 4x4 micro-tile, K-step 16, padded LDS (68).
// ---------------------------------------------------------------------------
template<int MODE>
__global__ __launch_bounds__(256) void gemm_bias(
    const float* __restrict__ X, const float* __restrict__ W,
    const float* __restrict__ bias, float* __restrict__ Y)
{
  __shared__ __attribute__((aligned(16))) float As[16][68];
  __shared__ __attribute__((aligned(16))) float Bs[16][68];
  const int tid = threadIdx.x;
  const int tx = tid & 15, ty = tid >> 4;
  const int m0 = blockIdx.x * 64, n0 = blockIdx.y * 64;
  const int lrow = tid >> 2;          // 0..63 : tile row loaded by this thread
  const int lk4  = (tid & 3) * 4;     // 0,4,8,12 : k-offset within tile

  float acc[4][4];
  #pragma unroll
  for (int j = 0; j < 4; ++j) {
    const float bv = bias[n0 + tx*4 + j];
    #pragma unroll
    for (int i = 0; i < 4; ++i) acc[i][j] = bv;
  }

  for (int kt = 0; kt < DMODEL/16; ++kt) {
    const float4 a  = *(const float4*)&X[(size_t)(m0 + lrow)*DMODEL + kt*16 + lk4];
    const float4 bw = *(const float4*)&W[(size_t)(n0 + lrow)*DMODEL + kt*16 + lk4];
    __syncthreads();   // previous iteration's readers are done
    As[lk4+0][lrow] = a.x;  As[lk4+1][lrow] = a.y;
    As[lk4+2][lrow] = a.z;  As[lk4+3][lrow] = a.w;
    Bs[lk4+0][lrow] = bw.x; Bs[lk4+1][lrow] = bw.y;
    Bs[lk4+2][lrow] = bw.z; Bs[lk4+3][lrow] = bw.w;
    __syncthreads();
    #pragma unroll
    for (int kk = 0; kk < 16; ++kk) {
      const float4 av = *(const float4*)&As[kk][ty*4];
      const float4 bv = *(const float4*)&Bs[kk][tx*4];
      acc[0][0] += av.x*bv.x; acc[0][1] += av.x*bv.y; acc[0][2] += av.x*bv.z; acc[0][3] += av.x*bv.w;
      acc[1][0] += av.y*bv.x; acc[1][1] += av.y*bv.y; acc[1][2] += av.y*bv.z; acc[1][3] += av.y*bv.w;
      acc[2][0] += av.z*bv.x; acc[2][1] += av.z*bv.y; acc[2][2] += av.z*bv.z; acc[2][3] += av.z*bv.w;
      acc[3][0] += av.w*bv.x; acc[3][1] += av.w*bv.y; acc[3][2] += av.w*bv.z; acc[3][3] += av.w*bv.w;
    }
  }

  #pragma unroll
  for (int i = 0; i < 4; ++i) {
    const int row = m0 + ty*4 + i;
    const int col = n0 + tx*4;
    const float4 v = make_float4(acc[i][0], acc[i][1], acc[i][2], acc[i][3]);
    if (MODE == 0) {
      const int b = row >> 10, l = row & (SEQ-1);
      const int h = col >> 6,  dk = col & (DKH-1);
      *(float4*)&Y[(((size_t)b*NHEADS + h)*SEQ + l)*DKH + dk] = v;
    } else {
      *(float4*)&Y[(size_t)row*DMODEL + col] = v;
    }
  }
}

// ---------------------------------------------------------------------------
// Flash attention with relative-position bias.
// Block = 256 threads = one (b, h, 64-row q-tile).  Online softmax over 16
// kv-tiles of 64.  Thread (rg,cg): rows {rg+16i}, score cols {cg+16j},
// output dims {cg*4..cg*4+3}.  Bias table P_s[row][33] precomputed per block
// (q_row . rel_table[j]) — the einsum collapses to a clipped-distance lookup.
// ---------------------------------------------------------------------------
__global__ __launch_bounds__(256) void attn_fwd(
    const float* __restrict__ qws, const float* __restrict__ kws,
    const float* __restrict__ vws, const float* __restrict__ rel,
    float* __restrict__ ctx)
{
  __shared__ __attribute__((aligned(16))) float q_s[64][68];
  __shared__ __attribute__((aligned(16))) float k_s[64][68];
  __shared__ __attribute__((aligned(16))) float v_s[64][68];
  __shared__ __attribute__((aligned(16))) float p_s[64][68];  // also rel_table staging
  __shared__ __attribute__((aligned(16))) float P_s[64][34];

  const int tid = threadIdx.x;
  const int cg = tid & 15;
  const int rg = tid >> 4;
  const int qt = blockIdx.x, h = blockIdx.y, b = blockIdx.z;
  const int l0 = qt * 64;

  const size_t headoff = ((size_t)b*NHEADS + h) * SEQ * DKH;
  const float* qbase = qws + headoff + (size_t)l0 * DKH;
  const float* kbase = kws + headoff;
  const float* vbase = vws + headoff;

  // ---- load Q tile (64x64), fully coalesced ----
  #pragma unroll
  for (int q = 0; q < 4; ++q) {
    const int f = q*1024 + tid*4;
    *(float4*)&q_s[f >> 6][f & 63] = *(const float4*)&qbase[f];
  }
  // ---- stage rel_table (33x64) flat in p_s region ----
  float* rt = &p_s[0][0];
  for (int f = tid*4; f < NREL*DKH; f += 1024)
    *(float4*)&rt[f] = *(const float4*)&rel[f];
  __syncthreads();

  // ---- P_s[r][j] = q_s[r][:] . rel_table[j][:]  (unscaled bias) ----
  for (int e = tid; e < 64*NREL; e += 256) {
    const int r = e / NREL;
    const int j = e - r*NREL;
    float s = 0.f;
    #pragma unroll
    for (int d = 0; d < DKH; d += 4) {
      const float4 a = *(const float4*)&q_s[r][d];
      const float4 t = *(const float4*)&rt[j*DKH + d];
      s += a.x*t.x + a.y*t.y + a.z*t.z + a.w*t.w;
    }
    P_s[r][j] = s;
  }

  float m_i[4], l_i[4];
  float4 acc[4];
  #pragma unroll
  for (int i = 0; i < 4; ++i) {
    m_i[i] = -1e30f; l_i[i] = 0.f;
    acc[i] = make_float4(0.f, 0.f, 0.f, 0.f);
  }

  for (int kt = 0; kt < SEQ/64; ++kt) {
    __syncthreads();  // protect k_s/v_s/p_s from previous iteration readers
    #pragma unroll
    for (int q = 0; q < 4; ++q) {
      const int f = q*1024 + tid*4;
      const int r = f >> 6, c = f & 63;
      *(float4*)&k_s[r][c] = *(const float4*)&kbase[(size_t)kt*4096 + f];
      *(float4*)&v_s[r][c] = *(const float4*)&vbase[(size_t)kt*4096 + f];
    }
    __syncthreads();

    // ---- scores s[i][j] = q[row_i] . k[col_j] ----
    float s[4][4];
    #pragma unroll
    for (int i = 0; i < 4; ++i)
      #pragma unroll
      for (int j = 0; j < 4; ++j) s[i][j] = 0.f;

    #pragma unroll
    for (int d4 = 0; d4 < 16; ++d4) {
      float4 qv[4], kv[4];
      #pragma unroll
      for (int i = 0; i < 4; ++i) qv[i] = *(const float4*)&q_s[rg + i*16][d4*4];
      #pragma unroll
      for (int j = 0; j < 4; ++j) kv[j] = *(const float4*)&k_s[cg + j*16][d4*4];
      #pragma unroll
      for (int i = 0; i < 4; ++i)
        #pragma unroll
        for (int j = 0; j < 4; ++j)
          s[i][j] += qv[i].x*kv[j].x + qv[i].y*kv[j].y + qv[i].z*kv[j].z + qv[i].w*kv[j].w;
    }

    // ---- bias + online softmax (rows reduced across the 16 cg lanes) ----
    #pragma unroll
    for (int i = 0; i < 4; ++i) {
      const int rloc = rg + i*16;
      const int rowg = l0 + rloc;
      float mt = -1e30f;
      #pragma unroll
      for (int j = 0; j < 4; ++j) {
        const int colg = kt*64 + cg + j*16;
        int dd = colg - rowg;
        dd = (dd < -16 ? -16 : (dd > 16 ? 16 : dd)) + 16;
        s[i][j] = s[i][j]*0.125f + P_s[rloc][dd];
        mt = fmaxf(mt, s[i][j]);
      }
      #pragma unroll
      for (int off = 1; off < 16; off <<= 1) mt = fmaxf(mt, __shfl_xor(mt, off, 64));
      const float mnew = fmaxf(m_i[i], mt);
      const float sf = __expf(m_i[i] - mnew);
      float ps = 0.f;
      #pragma unroll
      for (int j = 0; j < 4; ++j) { s[i][j] = __expf(s[i][j] - mnew); ps += s[i][j]; }
      #pragma unroll
      for (int off = 1; off < 16; off <<= 1) ps += __shfl_xor(ps, off, 64);
      m_i[i] = mnew;
      l_i[i] = l_i[i]*sf + ps;
      acc[i].x *= sf; acc[i].y *= sf; acc[i].z *= sf; acc[i].w *= sf;
      p_s[rloc][cg]      = s[i][0];
      p_s[rloc][cg + 16] = s[i][1];
      p_s[rloc][cg + 32] = s[i][2];
      p_s[rloc][cg + 48] = s[i][3];
    }
    __syncthreads();

    // ---- PV: acc[i][cg*4..+3] += sum_r p[row_i][r] * v[r][cg*4..+3] ----
    #pragma unroll
    for (int r4 = 0; r4 < 16; ++r4) {
      float4 pv[4];
      #pragma unroll
      for (int i = 0; i < 4; ++i) pv[i] = *(const float4*)&p_s[rg + i*16][r4*4];
      float4 vv[4];
      #pragma unroll
      for (int rr = 0; rr < 4; ++rr) vv[rr] = *(const float4*)&v_s[r4*4 + rr][cg*4];
      #pragma unroll
      for (int i = 0; i < 4; ++i) {
        acc[i].x += pv[i].x*vv[0].x + pv[i].y*vv[1].x + pv[i].z*vv[2].x + pv[i].w*vv[3].x;
        acc[i].y += pv[i].x*vv[0].y + pv[i].y*vv[1].y + pv[i].z*vv[2].y + pv[i].w*vv[3].y;
        acc[i].z += pv[i].x*vv[0].z + pv[i].y*vv[1].z + pv[i].z*vv[2].z + pv[i].w*vv[3].z;
        acc[i].w += pv[i].x*vv[0].w + pv[i].y*vv[1].w + pv[i].z*vv[2].w + pv[i].w*vv[3].w;
      }
    }
  }

  // ---- normalize and write context in [B,S,D] layout ----
  #pragma unroll
  for (int i = 0; i < 4; ++i) {
    const int rloc = rg + i*16;
    const float inv = 1.0f / l_i[i];
    const float4 o = make_float4(acc[i].x*inv, acc[i].y*inv, acc[i].z*inv, acc[i].w*inv);
    *(float4*)&ctx[(((size_t)b*SEQ) + l0 + rloc)*DMODEL + h*DKH + cg*4] = o;
  }
}

// ---------------------------------------------------------------------------
extern "C" void kernel_launch(void* const* d_in, const int* in_sizes, int n_in,
                              void* d_out, int out_size, void* d_ws, size_t ws_size,
                              hipStream_t stream)
{
  (void)in_sizes; (void)n_in; (void)out_size; (void)ws_size;
  const float* Q   = (const float*)d_in[0];
  const float* K   = (const float*)d_in[1];
  const float* V   = (const float*)d_in[2];
  const float* Wq  = (const float*)d_in[3];
  const float* bq  = (const float*)d_in[4];
  const float* Wk  = (const float*)d_in[5];
  const float* bk  = (const float*)d_in[6];
  const float* Wv  = (const float*)d_in[7];
  const float* bv  = (const float*)d_in[8];
  const float* Wo  = (const float*)d_in[9];
  const float* bo  = (const float*)d_in[10];
  const float* rel = (const float*)d_in[11];
  float* out = (float*)d_out;

  // workspace: q,k,v in [B,H,S,dk] + ctx in [B,S,D]  (4 x 16 MB = 64 MB)
  const size_t per = (size_t)BATCH*NHEADS*SEQ*DKH;
  float* qws = (float*)d_ws;
  float* kws = qws + per;
  float* vws = kws + per;
  float* ctx = vws + per;

  dim3 g1(MROWS/64, DMODEL/64);
  gemm_bias<0><<<g1, dim3(256), 0, stream>>>(Q, Wq, bq, qws);
  gemm_bias<0><<<g1, dim3(256), 0, stream>>>(K, Wk, bk, kws);
  gemm_bias<0><<<g1, dim3(256), 0, stream>>>(V, Wv, bv, vws);

  dim3 g2(SEQ/64, NHEADS, BATCH);
  attn_fwd<<<g2, dim3(256), 0, stream>>>(qws, kws, vws, rel, ctx);

  gemm_bias<1><<<g1, dim3(256), 0, stream>>>(ctx, Wo, bo, out);
}

// Round 3
// 490.581 us; speedup vs baseline: 2.4206x; 2.4206x over previous
//
#include <hip/hip_runtime.h>
#include <math.h>

#define DMODEL 1024
#define NHEADS 16
#define DKH    64
#define SEQ    1024
#define BATCH  4
#define NREL   33
#define MROWS  (BATCH*SEQ)   // 4096

typedef unsigned short u16;
typedef short s16x8 __attribute__((ext_vector_type(8)));
typedef float f32x4 __attribute__((ext_vector_type(4)));

#define MFMA16(a, b, c) __builtin_amdgcn_mfma_f32_16x16x32_bf16((a), (b), (c), 0, 0, 0)

// fp32 -> bf16 bits, round-nearest-even (no __bf16 dependency)
static __device__ __forceinline__ u16 f2b(float x) {
  unsigned u = __float_as_uint(x);
  u += 0x7fffu + ((u >> 16) & 1u);
  return (u16)(u >> 16);
}
static __device__ __forceinline__ float b2f(u16 b) {
  return __uint_as_float(((unsigned)b) << 16);
}

// ---------------------------------------------------------------------------
// fp32 -> (hi, lo) bf16-bits split.  hi[4096][1024], lo[4096][1024].
// ---------------------------------------------------------------------------
__global__ __launch_bounds__(256) void conv_split_a(
    const float* __restrict__ X, u16* __restrict__ hi, u16* __restrict__ lo)
{
  const int idx = blockIdx.x * 256 + threadIdx.x;   // one float4
  const float4 v = ((const float4*)X)[idx];
  ushort4 h, l;
  h.x = f2b(v.x); l.x = f2b(v.x - b2f(h.x));
  h.y = f2b(v.y); l.y = f2b(v.y - b2f(h.y));
  h.z = f2b(v.z); l.z = f2b(v.z - b2f(h.z));
  h.w = f2b(v.w); l.w = f2b(v.w - b2f(h.w));
  *(ushort4*)&hi[(size_t)idx * 4] = h;
  *(ushort4*)&lo[(size_t)idx * 4] = l;
}

// ---------------------------------------------------------------------------
// Weight fp32 [1024][1024] -> W2 [1024][3072] bf16-bits, B-pattern (hi|lo|hi).
// Paired with A-pattern (hi|hi|lo): sum = Ah*Bh + Ah*Bl + Al*Bh ~ fp32 product.
// ---------------------------------------------------------------------------
__global__ __launch_bounds__(256) void conv_split_b(
    const float* __restrict__ W, u16* __restrict__ W2)
{
  const int idx = blockIdx.x * 256 + threadIdx.x;   // one float4
  const int row = idx >> 8, c4 = idx & 255;
  const float4 v = ((const float4*)W)[idx];
  ushort4 h, l;
  h.x = f2b(v.x); l.x = f2b(v.x - b2f(h.x));
  h.y = f2b(v.y); l.y = f2b(v.y - b2f(h.y));
  h.z = f2b(v.z); l.z = f2b(v.z - b2f(h.z));
  h.w = f2b(v.w); l.w = f2b(v.w - b2f(h.w));
  u16* base = W2 + (size_t)row * 3072;
  *(ushort4*)&base[c4 * 4]        = h;
  *(ushort4*)&base[1024 + c4 * 4] = l;
  *(ushort4*)&base[2048 + c4 * 4] = h;
}

// ---------------------------------------------------------------------------
// MFMA GEMM: C[m][n] = sum_k A[m][k] * W[n][k] + bias[n]
// A regions (kt/32): 0->hi 1->hi 2->lo.  B = W2 (hi|lo|hi).
// NKT=96: split product.  NKT=32: plain bf16.
// 128x128 tile, 4 waves (2x2), per-wave 64x64 = 4x4 frags of 16x16x32.
// LDS rows padded to 40 u16 (80 B) -> conflict-free b128 fragment reads.
// OMODE 0: bf16 hi/lo pair -> [B,H,S,128]  (q / k for attention)
// OMODE 1: bf16 transposed -> [B,H,dk,S]   (vT: l-contiguous packed stores)
// OMODE 2: fp32            -> [4096][1024] (final output)
// ---------------------------------------------------------------------------
template<int NKT, int OMODE>
__global__ __launch_bounds__(256) void gemm_mfma(
    const u16* __restrict__ Ahi, const u16* __restrict__ Alo,
    const u16* __restrict__ B2,  const float* __restrict__ bias,
    void* __restrict__ outp)
{
  __shared__ __attribute__((aligned(16))) u16 As[128][40];
  __shared__ __attribute__((aligned(16))) u16 Bs[128][40];
  const int tid  = threadIdx.x;
  const int m0   = blockIdx.x * 128, n0 = blockIdx.y * 128;
  const int w    = tid >> 6, lane = tid & 63;
  const int wm   = w >> 1,  wn = w & 1;
  const int c    = lane & 15, g = lane >> 4;
  const int srow = tid >> 2, sc8 = (tid & 3) * 8;

  f32x4 acc[4][4];
  #pragma unroll
  for (int nf = 0; nf < 4; ++nf) {
    const float bv = bias[n0 + wn * 64 + nf * 16 + c];
    #pragma unroll
    for (int mf = 0; mf < 4; ++mf) acc[mf][nf] = (f32x4){bv, bv, bv, bv};
  }

  for (int kt = 0; kt < NKT; ++kt) {
    const int region = kt >> 5;
    const u16* Ab = (region == 2) ? Alo : Ahi;
    const int k0 = (kt & 31) * 32;
    const uint4 a0 = *(const uint4*)&Ab[(size_t)(m0 + srow)      * 1024 + k0 + sc8];
    const uint4 a1 = *(const uint4*)&Ab[(size_t)(m0 + srow + 64) * 1024 + k0 + sc8];
    const uint4 b0 = *(const uint4*)&B2[(size_t)(n0 + srow)      * 3072 + kt * 32 + sc8];
    const uint4 b1 = *(const uint4*)&B2[(size_t)(n0 + srow + 64) * 3072 + kt * 32 + sc8];
    __syncthreads();   // previous iteration's readers done
    *(uint4*)&As[srow][sc8]      = a0;
    *(uint4*)&As[srow + 64][sc8] = a1;
    *(uint4*)&Bs[srow][sc8]      = b0;
    *(uint4*)&Bs[srow + 64][sc8] = b1;
    __syncthreads();
    s16x8 af[4], bfr[4];
    #pragma unroll
    for (int mf = 0; mf < 4; ++mf) af[mf]  = *(const s16x8*)&As[wm * 64 + mf * 16 + c][g * 8];
    #pragma unroll
    for (int nf = 0; nf < 4; ++nf) bfr[nf] = *(const s16x8*)&Bs[wn * 64 + nf * 16 + c][g * 8];
    #pragma unroll
    for (int mf = 0; mf < 4; ++mf)
      #pragma unroll
      for (int nf = 0; nf < 4; ++nf)
        acc[mf][nf] = MFMA16(af[mf], bfr[nf], acc[mf][nf]);
  }

  // epilogue: m = m0+wm*64+mf*16+g*4+r ; n = n0+wn*64+nf*16+c
  #pragma unroll
  for (int mf = 0; mf < 4; ++mf) {
    #pragma unroll
    for (int nf = 0; nf < 4; ++nf) {
      const int mbase = m0 + wm * 64 + mf * 16 + g * 4;
      const int n = n0 + wn * 64 + nf * 16 + c;
      if (OMODE == 0) {
        u16* q2g = (u16*)outp;
        #pragma unroll
        for (int r = 0; r < 4; ++r) {
          const float o = acc[mf][nf][r];
          const u16 hv = f2b(o);
          const u16 lv = f2b(o - b2f(hv));
          const int m = mbase + r;
          const int b = m >> 10, sl = m & 1023, hh = n >> 6, dk = n & 63;
          const size_t base = ((size_t)(b * 16 + hh) * 1024 + sl) * 128 + dk;
          q2g[base]      = hv;
          q2g[base + 64] = lv;
        }
      } else if (OMODE == 1) {
        u16* vTg = (u16*)outp;
        ushort4 p;
        p.x = f2b(acc[mf][nf][0]);
        p.y = f2b(acc[mf][nf][1]);
        p.z = f2b(acc[mf][nf][2]);
        p.w = f2b(acc[mf][nf][3]);
        const int b = mbase >> 10, sl = mbase & 1023, hh = n >> 6, dk = n & 63;
        *(ushort4*)&vTg[((size_t)(b * 16 + hh) * 64 + dk) * 1024 + sl] = p;
      } else {
        float* Yo = (float*)outp;
        #pragma unroll
        for (int r = 0; r < 4; ++r)
          Yo[(size_t)(mbase + r) * 1024 + n] = acc[mf][nf][r];
      }
    }
  }
}

// ---------------------------------------------------------------------------
// MFMA flash attention + relative-position bias.
// Block = (qt, h, b), 4 waves; wave w owns q-rows w*16..w*16+15.
// QK^T: 3-term hi/lo split.  P.V: plain bf16 vs pre-transposed V.
// P crosses the D->A fragment layout mismatch through a wave-private LDS
// tile (in-wave ds ordering).  Tiles [64][72] u16: 144 B row stride ->
// conflict-free b128 reads.  LDS total 64512 B (fits 64 KB).
// ---------------------------------------------------------------------------
__global__ __launch_bounds__(256) void attn_mfma(
    const u16* __restrict__ q2g, const u16* __restrict__ k2g,
    const u16* __restrict__ vTg, const float* __restrict__ rel,
    u16* __restrict__ ctxh, u16* __restrict__ ctxl)
{
  __shared__ __attribute__((aligned(16))) u16 qh_s[64][72];
  __shared__ __attribute__((aligned(16))) u16 ql_s[64][72];
  __shared__ __attribute__((aligned(16))) u16 kh_s[64][72];
  __shared__ __attribute__((aligned(16))) u16 kl_s[64][72];
  __shared__ __attribute__((aligned(16))) u16 vT_s[64][72];
  __shared__ __attribute__((aligned(16))) u16 p_s [64][72];
  __shared__ __attribute__((aligned(16))) float bias_s[64][36];

  const int tid = threadIdx.x;
  const int w = tid >> 6, lane = tid & 63;
  const int c = lane & 15, g = lane >> 4;
  const int qt = blockIdx.x, hd = blockIdx.y, b = blockIdx.z;
  const int l0 = qt * 64;
  const int bh = b * 16 + hd;
  const int srow = tid >> 3, c8 = (tid & 7) * 8;

  // ---- stage q hi/lo (64 rows x 64) ----
  const u16* qsrc = q2g + ((size_t)bh * 1024 + l0) * 128;
  #pragma unroll
  for (int it = 0; it < 2; ++it) {
    const int r = it * 32 + srow;
    *(uint4*)&qh_s[r][c8] = *(const uint4*)&qsrc[r * 128 + c8];
    *(uint4*)&ql_s[r][c8] = *(const uint4*)&qsrc[r * 128 + 64 + c8];
  }
  __syncthreads();

  // ---- bias table: bias_s[r][j] = q_r . rel[j]  (q = hi+lo) ----
  for (int e = tid; e < 64 * NREL; e += 256) {
    const int r = e / NREL;
    const int j = e - r * NREL;
    float s = 0.f;
    #pragma unroll
    for (int d8 = 0; d8 < 8; ++d8) {
      #pragma unroll
      for (int jj = 0; jj < 8; ++jj) {
        const int d = d8 * 8 + jj;
        s += (b2f(qh_s[r][d]) + b2f(ql_s[r][d])) * rel[j * 64 + d];
      }
    }
    bias_s[r][j] = s;
  }

  // ---- per-wave q fragments (cached across kv tiles) ----
  s16x8 qhf[2], qlf[2];
  #pragma unroll
  for (int ks = 0; ks < 2; ++ks) {
    qhf[ks] = *(const s16x8*)&qh_s[w * 16 + c][ks * 32 + g * 8];
    qlf[ks] = *(const s16x8*)&ql_s[w * 16 + c][ks * 32 + g * 8];
  }

  float mr[4], ls[4];
  f32x4 oacc[4];
  #pragma unroll
  for (int r = 0; r < 4; ++r) { mr[r] = -1e30f; ls[r] = 0.f; }
  #pragma unroll
  for (int fd = 0; fd < 4; ++fd) oacc[fd] = (f32x4){0.f, 0.f, 0.f, 0.f};

  const u16* vbase = vTg + (size_t)bh * 64 * 1024;

  for (int kt = 0; kt < SEQ / 64; ++kt) {
    __syncthreads();   // previous tile's readers done (covers bias_s at kt=0)
    const u16* ksrc = k2g + ((size_t)bh * 1024 + kt * 64) * 128;
    #pragma unroll
    for (int it = 0; it < 2; ++it) {
      const int r = it * 32 + srow;
      *(uint4*)&kh_s[r][c8] = *(const uint4*)&ksrc[r * 128 + c8];
      *(uint4*)&kl_s[r][c8] = *(const uint4*)&ksrc[r * 128 + 64 + c8];
      *(uint4*)&vT_s[r][c8] = *(const uint4*)&vbase[(size_t)r * 1024 + kt * 64 + c8];
    }
    __syncthreads();

    // ---- scores: 3-term split QK^T ----
    f32x4 sc[4];
    #pragma unroll
    for (int f = 0; f < 4; ++f) sc[f] = (f32x4){0.f, 0.f, 0.f, 0.f};
    #pragma unroll
    for (int f = 0; f < 4; ++f) {
      #pragma unroll
      for (int ks = 0; ks < 2; ++ks) {
        const s16x8 kh = *(const s16x8*)&kh_s[f * 16 + c][ks * 32 + g * 8];
        const s16x8 kl = *(const s16x8*)&kl_s[f * 16 + c][ks * 32 + g * 8];
        sc[f] = MFMA16(qhf[ks], kh, sc[f]);
        sc[f] = MFMA16(qhf[ks], kl, sc[f]);
        sc[f] = MFMA16(qlf[ks], kh, sc[f]);
      }
    }

    // ---- bias + online softmax (row = g*4+r, 16 c-lanes per row) ----
    const int qb = w * 16 + g * 4;
    #pragma unroll
    for (int r = 0; r < 4; ++r) {
      const int rowg = l0 + qb + r;
      float sv[4], vmax = -1e30f;
      #pragma unroll
      for (int f = 0; f < 4; ++f) {
        const int colg = kt * 64 + f * 16 + c;
        int dd = colg - rowg;
        dd = (dd < -16 ? -16 : (dd > 16 ? 16 : dd)) + 16;
        sv[f] = sc[f][r] * 0.125f + bias_s[qb + r][dd];
        vmax = fmaxf(vmax, sv[f]);
      }
      #pragma unroll
      for (int off = 1; off < 16; off <<= 1) vmax = fmaxf(vmax, __shfl_xor(vmax, off, 64));
      const float mnew = fmaxf(mr[r], vmax);
      const float sf = __expf(mr[r] - mnew);
      float psum = 0.f;
      #pragma unroll
      for (int f = 0; f < 4; ++f) { sv[f] = __expf(sv[f] - mnew); psum += sv[f]; }
      #pragma unroll
      for (int off = 1; off < 16; off <<= 1) psum += __shfl_xor(psum, off, 64);
      mr[r] = mnew;
      ls[r] = ls[r] * sf + psum;
      #pragma unroll
      for (int fd = 0; fd < 4; ++fd) oacc[fd][r] *= sf;
      #pragma unroll
      for (int f = 0; f < 4; ++f) p_s[qb + r][f * 16 + c] = f2b(sv[f]);
    }

    // ---- P.V (wave-private p_s rows; in-wave lgkm ordering, no barrier) ----
    #pragma unroll
    for (int ks = 0; ks < 2; ++ks) {
      const s16x8 pa = *(const s16x8*)&p_s[w * 16 + c][ks * 32 + g * 8];
      #pragma unroll
      for (int fd = 0; fd < 4; ++fd) {
        const s16x8 vb = *(const s16x8*)&vT_s[fd * 16 + c][ks * 32 + g * 8];
        oacc[fd] = MFMA16(pa, vb, oacc[fd]);
      }
    }
  }

  // ---- normalize, split, write ctx hi/lo [4096][1024] ----
  #pragma unroll
  for (int r = 0; r < 4; ++r) {
    const float inv = 1.0f / ls[r];
    const int row = l0 + w * 16 + g * 4 + r;
    #pragma unroll
    for (int fd = 0; fd < 4; ++fd) {
      const float o = oacc[fd][r] * inv;
      const u16 hv = f2b(o);
      const size_t a = ((size_t)b * 1024 + row) * 1024 + hd * 64 + fd * 16 + c;
      ctxh[a] = hv;
      ctxl[a] = f2b(o - b2f(hv));
    }
  }
}

// ---------------------------------------------------------------------------
extern "C" void kernel_launch(void* const* d_in, const int* in_sizes, int n_in,
                              void* d_out, int out_size, void* d_ws, size_t ws_size,
                              hipStream_t stream)
{
  (void)in_sizes; (void)n_in; (void)out_size; (void)ws_size;
  const float* Q   = (const float*)d_in[0];
  const float* K   = (const float*)d_in[1];
  const float* V   = (const float*)d_in[2];
  const float* Wq  = (const float*)d_in[3];
  const float* bq  = (const float*)d_in[4];
  const float* Wk  = (const float*)d_in[5];
  const float* bk  = (const float*)d_in[6];
  const float* Wv  = (const float*)d_in[7];
  const float* bv  = (const float*)d_in[8];
  const float* Wo  = (const float*)d_in[9];
  const float* bo  = (const float*)d_in[10];
  const float* rel = (const float*)d_in[11];
  float* out = (float*)d_out;

  // workspace (bytes), total 65,011,712 <= 67,108,864 proven in round 0:
  //   Xhi 0 (8.39M) | Xlo 8.39M | W2 16.78M (6.29M) | q2g 23.07M (16.78M)
  //   | k2g 39.85M (16.78M) | vTg 56.62M (8.39M)
  // ctxh/ctxl reuse Xhi/Xlo after the V-GEMM (attention writes them).
  char* ws = (char*)d_ws;
  u16* Xhi = (u16*)(ws);
  u16* Xlo = (u16*)(ws + 8388608);
  u16* W2  = (u16*)(ws + 16777216);
  u16* q2g = (u16*)(ws + 23068672);
  u16* k2g = (u16*)(ws + 39845888);
  u16* vTg = (u16*)(ws + 56623104);
  u16* ctxh = (u16*)(ws);
  u16* ctxl = (u16*)(ws + 8388608);

  const dim3 blk(256);
  const dim3 gg(32, 8);      // 4096/128 x 1024/128
  const dim3 ga(SEQ / 64, NHEADS, BATCH);

  // Q projection (split)
  conv_split_b<<<1024, blk, 0, stream>>>(Wq, W2);
  conv_split_a<<<4096, blk, 0, stream>>>(Q, Xhi, Xlo);
  gemm_mfma<96, 0><<<gg, blk, 0, stream>>>(Xhi, Xlo, W2, bq, q2g);
  // K projection (split)
  conv_split_b<<<1024, blk, 0, stream>>>(Wk, W2);
  conv_split_a<<<4096, blk, 0, stream>>>(K, Xhi, Xlo);
  gemm_mfma<96, 0><<<gg, blk, 0, stream>>>(Xhi, Xlo, W2, bk, k2g);
  // V projection (plain bf16, transposed output)
  conv_split_b<<<1024, blk, 0, stream>>>(Wv, W2);
  conv_split_a<<<4096, blk, 0, stream>>>(V, Xhi, Xlo);
  gemm_mfma<32, 1><<<gg, blk, 0, stream>>>(Xhi, Xlo, W2, bv, vTg);
  // attention (writes ctx hi/lo over the X region)
  attn_mfma<<<ga, blk, 0, stream>>>(q2g, k2g, vTg, rel, ctxh, ctxl);
  // output projection (split)
  conv_split_b<<<1024, blk, 0, stream>>>(Wo, W2);
  gemm_mfma<96, 2><<<gg, blk, 0, stream>>>(ctxh, ctxl, W2, bo, out);
}

// Round 4
// 465.776 us; speedup vs baseline: 2.5495x; 1.0533x over previous
//
#include <hip/hip_runtime.h>
#include <math.h>

#define DMODEL 1024
#define NHEADS 16
#define DKH    64
#define SEQ    1024
#define BATCH  4
#define NREL   33

typedef unsigned short u16;
typedef unsigned int   u32;
typedef short s16x8 __attribute__((ext_vector_type(8)));
typedef u16   u16x8 __attribute__((ext_vector_type(8)));
typedef float f32x4 __attribute__((ext_vector_type(4)));

#define MFMA16(a, b, c) __builtin_amdgcn_mfma_f32_16x16x32_bf16((a), (b), (c), 0, 0, 0)

// fp32 -> bf16 bits, round-nearest-even
static __device__ __forceinline__ u16 f2b(float x) {
  unsigned u = __float_as_uint(x);
  u += 0x7fffu + ((u >> 16) & 1u);
  return (u16)(u >> 16);
}
static __device__ __forceinline__ float b2f(u16 b) {
  return __uint_as_float(((unsigned)b) << 16);
}

// async global->LDS, 16 bytes per lane (dest = wave-uniform base + lane*16)
static __device__ __forceinline__ void gload16(const void* g, void* l) {
  __builtin_amdgcn_global_load_lds(
      (const __attribute__((address_space(1))) u32*)g,
      (__attribute__((address_space(3))) u32*)l, 16, 0, 0);
}

// ---------------------------------------------------------------------------
// fp32 [N] -> bf16 [N]  (8 elements/thread)
// ---------------------------------------------------------------------------
__global__ __launch_bounds__(256) void conv_x(
    const float* __restrict__ X, u16* __restrict__ Y)
{
  const int i8 = (blockIdx.x * 256 + threadIdx.x) * 8;
  const float4 v0 = *(const float4*)&X[i8];
  const float4 v1 = *(const float4*)&X[i8 + 4];
  u16x8 o;
  o[0] = f2b(v0.x); o[1] = f2b(v0.y); o[2] = f2b(v0.z); o[3] = f2b(v0.w);
  o[4] = f2b(v1.x); o[5] = f2b(v1.y); o[6] = f2b(v1.z); o[7] = f2b(v1.w);
  *(u16x8*)&Y[i8] = o;
}

// ---------------------------------------------------------------------------
// W fp32 [1024][1024] -> W2 [1024][2048] bf16 (hi | lo).  B-side split:
// A*W2 over K=2048 = A*hi(W) + A*lo(W) ~= A*W with fp32-grade W.
// ---------------------------------------------------------------------------
__global__ __launch_bounds__(256) void conv_w(
    const float* __restrict__ W, u16* __restrict__ W2)
{
  const int i8 = (blockIdx.x * 256 + threadIdx.x) * 8;
  const int row = i8 >> 10, col = i8 & 1023;
  const float4 v0 = *(const float4*)&W[i8];
  const float4 v1 = *(const float4*)&W[i8 + 4];
  u16x8 h, l;
  h[0] = f2b(v0.x); l[0] = f2b(v0.x - b2f(h[0]));
  h[1] = f2b(v0.y); l[1] = f2b(v0.y - b2f(h[1]));
  h[2] = f2b(v0.z); l[2] = f2b(v0.z - b2f(h[2]));
  h[3] = f2b(v0.w); l[3] = f2b(v0.w - b2f(h[3]));
  h[4] = f2b(v1.x); l[4] = f2b(v1.x - b2f(h[4]));
  h[5] = f2b(v1.y); l[5] = f2b(v1.y - b2f(h[5]));
  h[6] = f2b(v1.z); l[6] = f2b(v1.z - b2f(h[6]));
  h[7] = f2b(v1.w); l[7] = f2b(v1.w - b2f(h[7]));
  u16* base = W2 + (size_t)row * 2048;
  *(u16x8*)&base[col]        = h;
  *(u16x8*)&base[1024 + col] = l;
}

// ---------------------------------------------------------------------------
// GEMM body: C[m][n] = sum_k A[m][k] * W[n][k] + bias[n],  A bf16 [4096][1024],
// B2 [1024][2048] (hi|lo; A col = (kt&31)*32).  Tile 64x128, BK=32, 64 kt.
// 4 waves (2m x 2n), per-wave 32x64 = 2x4 frags of 16x16x32.
// Staging via global_load_lds width 16, linear LDS (m97 structure).
// omode 0: bf16 -> [B,H,S,64] (q/k)   1: bf16 -> [B,H,dk,S] (vT)
//       2: fp32 -> [4096][1024]
// ---------------------------------------------------------------------------
__device__ __forceinline__ void gemm_body(
    const u16* __restrict__ A, const u16* __restrict__ B2,
    const float* __restrict__ bias, void* __restrict__ outp, const int omode)
{
  __shared__ __attribute__((aligned(16))) u16 As[64][32];
  __shared__ __attribute__((aligned(16))) u16 Bs[128][32];
  const int tid = threadIdx.x;
  const int m0 = blockIdx.x * 64, n0 = blockIdx.y * 128;
  const int w = tid >> 6, lane = tid & 63;
  const int wm = w >> 1, wn = w & 1;
  const int c = lane & 15, g = lane >> 4;

  // staging: thread -> (row, 16B chunk); LDS linear offset = tid*16 (+i*4096)
  const int srow = tid >> 2, schunk = (tid & 3) * 8;
  const u16* aptr  = &A [(size_t)(m0 + srow) * 1024 + schunk];
  const u16* bptr0 = &B2[(size_t)(n0 + srow) * 2048 + schunk];
  const u16* bptr1 = bptr0 + (size_t)64 * 2048;
  char* aldst  = (char*)&As[0][0] + w * 1024;
  char* bldst0 = (char*)&Bs[0][0] + w * 1024;
  char* bldst1 = bldst0 + 4096;

  f32x4 acc[2][4];
  #pragma unroll
  for (int nf = 0; nf < 4; ++nf) {
    const float bv = bias[n0 + wn * 64 + nf * 16 + c];
    acc[0][nf] = (f32x4){bv, bv, bv, bv};
    acc[1][nf] = (f32x4){bv, bv, bv, bv};
  }

  for (int kt = 0; kt < 64; ++kt) {
    const int ksrc = (kt & 31) * 32;
    __syncthreads();                       // previous iteration's readers done
    gload16(aptr + ksrc, aldst);
    gload16(bptr0 + kt * 32, bldst0);
    gload16(bptr1 + kt * 32, bldst1);
    __syncthreads();                       // vmcnt(0) drain -> LDS ready
    s16x8 af[2], bfr[4];
    #pragma unroll
    for (int mf = 0; mf < 2; ++mf) af[mf]  = *(const s16x8*)&As[wm * 32 + mf * 16 + c][g * 8];
    #pragma unroll
    for (int nf = 0; nf < 4; ++nf) bfr[nf] = *(const s16x8*)&Bs[wn * 64 + nf * 16 + c][g * 8];
    #pragma unroll
    for (int mf = 0; mf < 2; ++mf)
      #pragma unroll
      for (int nf = 0; nf < 4; ++nf)
        acc[mf][nf] = MFMA16(af[mf], bfr[nf], acc[mf][nf]);
  }

  // epilogue: m = m0+wm*32+mf*16+g*4+r ; n = n0+wn*64+nf*16+c
  #pragma unroll
  for (int mf = 0; mf < 2; ++mf) {
    #pragma unroll
    for (int nf = 0; nf < 4; ++nf) {
      const int mbase = m0 + wm * 32 + mf * 16 + g * 4;
      const int n = n0 + wn * 64 + nf * 16 + c;
      if (omode == 0) {
        u16* O = (u16*)outp;
        #pragma unroll
        for (int r = 0; r < 4; ++r) {
          const int m = mbase + r;
          const int b = m >> 10, sl = m & 1023, h = n >> 6, dk = n & 63;
          O[((size_t)(b * 16 + h) * 1024 + sl) * 64 + dk] = f2b(acc[mf][nf][r]);
        }
      } else if (omode == 1) {
        u16* O = (u16*)outp;
        ushort4 pk;
        pk.x = f2b(acc[mf][nf][0]);
        pk.y = f2b(acc[mf][nf][1]);
        pk.z = f2b(acc[mf][nf][2]);
        pk.w = f2b(acc[mf][nf][3]);
        const int b = mbase >> 10, sl = mbase & 1023, h = n >> 6, dk = n & 63;
        *(ushort4*)&O[((size_t)(b * 16 + h) * 64 + dk) * 1024 + sl] = pk;
      } else {
        float* O = (float*)outp;
        #pragma unroll
        for (int r = 0; r < 4; ++r)
          O[(size_t)(mbase + r) * 1024 + n] = acc[mf][nf][r];
      }
    }
  }
}

__global__ __launch_bounds__(256) void gemm_qkv(
    const u16* __restrict__ Xq, const u16* __restrict__ Xk, const u16* __restrict__ Xv,
    const u16* __restrict__ Wq2, const u16* __restrict__ Wk2, const u16* __restrict__ Wv2,
    const float* __restrict__ bq, const float* __restrict__ bk, const float* __restrict__ bv,
    u16* __restrict__ q2g, u16* __restrict__ k2g, u16* __restrict__ vTg)
{
  const int z = blockIdx.z;
  const u16* A    = z == 0 ? Xq  : (z == 1 ? Xk  : Xv);
  const u16* B2   = z == 0 ? Wq2 : (z == 1 ? Wk2 : Wv2);
  const float* bb = z == 0 ? bq  : (z == 1 ? bk  : bv);
  void* O         = z == 0 ? (void*)q2g : (z == 1 ? (void*)k2g : (void*)vTg);
  gemm_body(A, B2, bb, O, z == 2 ? 1 : 0);
}

__global__ __launch_bounds__(256) void gemm_out2(
    const u16* __restrict__ A, const u16* __restrict__ B2,
    const float* __restrict__ bias, float* __restrict__ out)
{
  gemm_body(A, B2, bias, out, 2);
}

// ---------------------------------------------------------------------------
// MFMA flash attention, rel-pos bias.  Block = (qt, h, b), 4 waves; wave w
// owns q-rows w*16..+15.  K/V fragments loaded DIRECTLY from global (L2-hot:
// 256 KB per head, shared by 16 q-blocks) -> no K/V LDS, no per-tile barriers.
// q: one-time LDS stage (bias table) + register fragments.  P crosses the
// D->A layout mismatch through wave-private padded LDS.
// ---------------------------------------------------------------------------
__global__ __launch_bounds__(256) void attn2(
    const u16* __restrict__ q2g, const u16* __restrict__ k2g,
    const u16* __restrict__ vTg, const float* __restrict__ rel,
    u16* __restrict__ ctx)
{
  __shared__ __attribute__((aligned(16))) u16 q_s[64][64];
  __shared__ __attribute__((aligned(16))) u16 p_s[64][72];
  __shared__ __attribute__((aligned(16))) float bias_s[64][34];

  const int tid = threadIdx.x;
  const int w = tid >> 6, lane = tid & 63;
  const int c = lane & 15, g = lane >> 4;
  const int qt = blockIdx.x, hd = blockIdx.y, b = blockIdx.z;
  const int l0 = qt * 64;
  const int bh = b * 16 + hd;

  // ---- one-time q stage (64x64 bf16) ----
  const u16* qsrc = q2g + ((size_t)bh * 1024 + l0) * 64;
  #pragma unroll
  for (int i = 0; i < 2; ++i) {
    const int f16 = tid * 2 + i;          // 16B chunk index
    const int r = f16 >> 3, ch = (f16 & 7) * 8;
    *(uint4*)&q_s[r][ch] = *(const uint4*)&qsrc[r * 64 + ch];
  }
  __syncthreads();

  // ---- bias table: bias_s[r][j] = q_r . rel[j] ----
  for (int e = tid; e < 64 * NREL; e += 256) {
    const int r = e / NREL;
    const int j = e - r * NREL;
    float s = 0.f;
    #pragma unroll
    for (int d = 0; d < DKH; ++d)
      s += b2f(q_s[r][d]) * rel[j * 64 + d];
    bias_s[r][j] = s;
  }

  // ---- per-wave q fragments ----
  s16x8 qf[2];
  #pragma unroll
  for (int ks = 0; ks < 2; ++ks)
    qf[ks] = *(const s16x8*)&q_s[w * 16 + c][ks * 32 + g * 8];
  __syncthreads();                         // bias_s ready

  float mr[4], ls[4];
  f32x4 oacc[4];
  #pragma unroll
  for (int r = 0; r < 4; ++r) { mr[r] = -1e30f; ls[r] = 0.f; }
  #pragma unroll
  for (int fd = 0; fd < 4; ++fd) oacc[fd] = (f32x4){0.f, 0.f, 0.f, 0.f};

  const u16* kbase = k2g + (size_t)bh * 1024 * 64;
  const u16* vbase = vTg + (size_t)bh * 64 * 1024;
  const int qb = w * 16 + g * 4;

  for (int kt = 0; kt < SEQ / 64; ++kt) {
    // ---- scores: direct-global K fragments ----
    f32x4 sc[4];
    #pragma unroll
    for (int f = 0; f < 4; ++f) sc[f] = (f32x4){0.f, 0.f, 0.f, 0.f};
    #pragma unroll
    for (int f = 0; f < 4; ++f) {
      #pragma unroll
      for (int ks = 0; ks < 2; ++ks) {
        const s16x8 kf = *(const s16x8*)&kbase[(size_t)(kt * 64 + f * 16 + c) * 64 + ks * 32 + g * 8];
        sc[f] = MFMA16(qf[ks], kf, sc[f]);
      }
    }

    // ---- bias + online softmax (row = qb+r, 16 c-lanes per row) ----
    #pragma unroll
    for (int r = 0; r < 4; ++r) {
      const int rowg = l0 + qb + r;
      float sv[4], vmax = -1e30f;
      #pragma unroll
      for (int f = 0; f < 4; ++f) {
        const int colg = kt * 64 + f * 16 + c;
        int dd = colg - rowg;
        dd = (dd < -16 ? -16 : (dd > 16 ? 16 : dd)) + 16;
        sv[f] = sc[f][r] * 0.125f + bias_s[qb + r][dd];
        vmax = fmaxf(vmax, sv[f]);
      }
      #pragma unroll
      for (int off = 1; off < 16; off <<= 1) vmax = fmaxf(vmax, __shfl_xor(vmax, off, 64));
      const float mnew = fmaxf(mr[r], vmax);
      const float sf = __expf(mr[r] - mnew);
      float psum = 0.f;
      #pragma unroll
      for (int f = 0; f < 4; ++f) { sv[f] = __expf(sv[f] - mnew); psum += sv[f]; }
      #pragma unroll
      for (int off = 1; off < 16; off <<= 1) psum += __shfl_xor(psum, off, 64);
      mr[r] = mnew;
      ls[r] = ls[r] * sf + psum;
      #pragma unroll
      for (int fd = 0; fd < 4; ++fd) oacc[fd][r] *= sf;
      #pragma unroll
      for (int f = 0; f < 4; ++f) p_s[qb + r][f * 16 + c] = f2b(sv[f]);
    }

    // ---- P.V: wave-private p_s + direct-global V fragments ----
    #pragma unroll
    for (int ks = 0; ks < 2; ++ks) {
      const s16x8 pa = *(const s16x8*)&p_s[w * 16 + c][ks * 32 + g * 8];
      #pragma unroll
      for (int fd = 0; fd < 4; ++fd) {
        const s16x8 vb = *(const s16x8*)&vbase[(size_t)(fd * 16 + c) * 1024 + kt * 64 + ks * 32 + g * 8];
        oacc[fd] = MFMA16(pa, vb, oacc[fd]);
      }
    }
  }

  // ---- normalize, write ctx bf16 [4096][1024] ----
  #pragma unroll
  for (int r = 0; r < 4; ++r) {
    const float inv = 1.0f / ls[r];
    const int row = l0 + w * 16 + g * 4 + r;
    #pragma unroll
    for (int fd = 0; fd < 4; ++fd)
      ctx[((size_t)b * 1024 + row) * 1024 + hd * 64 + fd * 16 + c] = f2b(oacc[fd][r] * inv);
  }
}

// ---------------------------------------------------------------------------
extern "C" void kernel_launch(void* const* d_in, const int* in_sizes, int n_in,
                              void* d_out, int out_size, void* d_ws, size_t ws_size,
                              hipStream_t stream)
{
  (void)in_sizes; (void)n_in; (void)out_size; (void)ws_size;
  const float* Q   = (const float*)d_in[0];
  const float* K   = (const float*)d_in[1];
  const float* V   = (const float*)d_in[2];
  const float* Wq  = (const float*)d_in[3];
  const float* bq  = (const float*)d_in[4];
  const float* Wk  = (const float*)d_in[5];
  const float* bk  = (const float*)d_in[6];
  const float* Wv  = (const float*)d_in[7];
  const float* bv  = (const float*)d_in[8];
  const float* Wo  = (const float*)d_in[9];
  const float* bo  = (const float*)d_in[10];
  const float* rel = (const float*)d_in[11];
  float* out = (float*)d_out;

  // ws map (bytes), peak 62,914,560 <= 65,011,712 proven:
  //   Xq 0 | Xk 8.39M | Xv 16.78M | W2q 25.17M | W2k 29.36M | W2v 33.55M
  //   | q2g 37.75M | k2g 46.14M | vTg 54.53M
  // ctx reuses Xq after QKV GEMM; W2o reuses Xk after QKV GEMM.
  char* ws = (char*)d_ws;
  u16* Xq  = (u16*)(ws);
  u16* Xk  = (u16*)(ws + 8388608);
  u16* Xv  = (u16*)(ws + 16777216);
  u16* W2q = (u16*)(ws + 25165824);
  u16* W2k = (u16*)(ws + 29360128);
  u16* W2v = (u16*)(ws + 33554432);
  u16* q2g = (u16*)(ws + 37748736);
  u16* k2g = (u16*)(ws + 46137344);
  u16* vTg = (u16*)(ws + 54525952);
  u16* ctx = Xq;
  u16* W2o = Xk;

  const dim3 blk(256);
  conv_x<<<2048, blk, 0, stream>>>(Q, Xq);
  conv_x<<<2048, blk, 0, stream>>>(K, Xk);
  conv_x<<<2048, blk, 0, stream>>>(V, Xv);
  conv_w<<<512, blk, 0, stream>>>(Wq, W2q);
  conv_w<<<512, blk, 0, stream>>>(Wk, W2k);
  conv_w<<<512, blk, 0, stream>>>(Wv, W2v);

  gemm_qkv<<<dim3(64, 8, 3), blk, 0, stream>>>(Xq, Xk, Xv, W2q, W2k, W2v,
                                               bq, bk, bv, q2g, k2g, vTg);

  attn2<<<dim3(SEQ / 64, NHEADS, BATCH), blk, 0, stream>>>(q2g, k2g, vTg, rel, ctx);

  conv_w<<<512, blk, 0, stream>>>(Wo, W2o);
  gemm_out2<<<dim3(64, 8), blk, 0, stream>>>(ctx, W2o, bo, out);
}

// Round 5
// 370.302 us; speedup vs baseline: 3.2068x; 1.2578x over previous
//
#include <hip/hip_runtime.h>
#include <math.h>

#define DMODEL 1024
#define NHEADS 16
#define DKH    64
#define SEQ    1024
#define BATCH  4
#define NREL   33

typedef unsigned short u16;
typedef unsigned int   u32;
typedef short s16x8 __attribute__((ext_vector_type(8)));
typedef u16   u16x8 __attribute__((ext_vector_type(8)));
typedef float f32x4 __attribute__((ext_vector_type(4)));

#define MFMA16(a, b, c) __builtin_amdgcn_mfma_f32_16x16x32_bf16((a), (b), (c), 0, 0, 0)

// fp32 -> bf16 bits, round-nearest-even
static __device__ __forceinline__ u16 f2b(float x) {
  unsigned u = __float_as_uint(x);
  u += 0x7fffu + ((u >> 16) & 1u);
  return (u16)(u >> 16);
}
static __device__ __forceinline__ float b2f(u16 b) {
  return __uint_as_float(((unsigned)b) << 16);
}

// async global->LDS, 16 B/lane (dest = wave-uniform base + lane*16)
static __device__ __forceinline__ void gload16(const void* g, void* l) {
  __builtin_amdgcn_global_load_lds(
      (const __attribute__((address_space(1))) u32*)g,
      (__attribute__((address_space(3))) u32*)l, 16, 0, 0);
}

// ---------------------------------------------------------------------------
// fp32 [N] -> bf16 [N]  (8 elements/thread)
// ---------------------------------------------------------------------------
__global__ __launch_bounds__(256) void conv_x(
    const float* __restrict__ X, u16* __restrict__ Y)
{
  const int i8 = (blockIdx.x * 256 + threadIdx.x) * 8;
  const float4 v0 = *(const float4*)&X[i8];
  const float4 v1 = *(const float4*)&X[i8 + 4];
  u16x8 o;
  o[0] = f2b(v0.x); o[1] = f2b(v0.y); o[2] = f2b(v0.z); o[3] = f2b(v0.w);
  o[4] = f2b(v1.x); o[5] = f2b(v1.y); o[6] = f2b(v1.z); o[7] = f2b(v1.w);
  *(u16x8*)&Y[i8] = o;
}

// ---------------------------------------------------------------------------
// W fp32 [1024][1024] -> W2 [1024][2048] bf16 (hi | lo).  B-side split:
// A*W2 over K=2048 = A*hi(W) + A*lo(W) ~= A*W with fp32-grade W.
// ---------------------------------------------------------------------------
__global__ __launch_bounds__(256) void conv_w(
    const float* __restrict__ W, u16* __restrict__ W2)
{
  const int i8 = (blockIdx.x * 256 + threadIdx.x) * 8;
  const int row = i8 >> 10, col = i8 & 1023;
  const float4 v0 = *(const float4*)&W[i8];
  const float4 v1 = *(const float4*)&W[i8 + 4];
  u16x8 h, l;
  h[0] = f2b(v0.x); l[0] = f2b(v0.x - b2f(h[0]));
  h[1] = f2b(v0.y); l[1] = f2b(v0.y - b2f(h[1]));
  h[2] = f2b(v0.z); l[2] = f2b(v0.z - b2f(h[2]));
  h[3] = f2b(v0.w); l[3] = f2b(v0.w - b2f(h[3]));
  h[4] = f2b(v1.x); l[4] = f2b(v1.x - b2f(h[4]));
  h[5] = f2b(v1.y); l[5] = f2b(v1.y - b2f(h[5]));
  h[6] = f2b(v1.z); l[6] = f2b(v1.z - b2f(h[6]));
  h[7] = f2b(v1.w); l[7] = f2b(v1.w - b2f(h[7]));
  u16* base = W2 + (size_t)row * 2048;
  *(u16x8*)&base[col]        = h;
  *(u16x8*)&base[1024 + col] = l;
}

// ---------------------------------------------------------------------------
// GEMM: C[m][n] = sum_k A[m][k]*W[n][k] + bias[n].  A bf16 [4096][1024],
// B2 [1024][2048] (hi|lo -> A col = (kt&31)*32).  m97 geometry: 128x128 tile,
// BK=32, 64 K-steps, 4 waves (2x2), per-wave 64x64 = 4x4 frags 16x16x32.
// Double-buffered gload_lds, 2-phase prefetch (stage kt+1, compute kt, one
// barrier per K-step).
// omode 0: bf16 -> [B,H,S,64] (q/k)  1: bf16 -> [B,H,dk,S] (vT)  2: fp32
// ---------------------------------------------------------------------------
__device__ __forceinline__ void gemm_body(
    const u16* __restrict__ A, const u16* __restrict__ B2,
    const float* __restrict__ bias, void* __restrict__ outp, const int omode)
{
  __shared__ __attribute__((aligned(16))) u16 As[2][128][32];
  __shared__ __attribute__((aligned(16))) u16 Bs[2][128][32];
  const int tid = threadIdx.x;
  const int m0 = blockIdx.x * 128, n0 = blockIdx.y * 128;
  const int w = tid >> 6, lane = tid & 63;
  const int wm = w >> 1, wn = w & 1;
  const int c = lane & 15, g = lane >> 4;

  // staging: chunk D = i*256+tid -> (row = D>>2, kcol = (D&3)*8); dest D*16 B
  const int sr = tid >> 2;            // row for i=0 (i=1: +64)
  const int kc = (tid & 3) * 8;
  const u16* aP = A  + (size_t)(m0 + sr) * 1024 + kc;
  const u16* bP = B2 + (size_t)(n0 + sr) * 2048 + kc;
  char* aD = (char*)As + w * 1024;    // + buf*8192 + i*4096 (wave-uniform)
  char* bD = (char*)Bs + w * 1024;

  f32x4 acc[4][4];
  #pragma unroll
  for (int nf = 0; nf < 4; ++nf) {
    const float bv = bias[n0 + wn * 64 + nf * 16 + c];
    #pragma unroll
    for (int mf = 0; mf < 4; ++mf) acc[mf][nf] = (f32x4){bv, bv, bv, bv};
  }

  // prologue: stage kt=0 into buf 0
  gload16(aP,              aD);
  gload16(aP + 64 * 1024,  aD + 4096);
  gload16(bP,              bD);
  gload16(bP + 64 * 2048,  bD + 4096);
  __syncthreads();

  for (int kt = 0; kt < 64; ++kt) {
    const int cur = kt & 1;
    if (kt < 63) {
      const int kn = kt + 1;
      const u16* a = aP + (kn & 31) * 32;
      const u16* bb = bP + kn * 32;
      char* ad = aD + (cur ^ 1) * 8192;
      char* bd = bD + (cur ^ 1) * 8192;
      gload16(a,             ad);
      gload16(a + 64 * 1024, ad + 4096);
      gload16(bb,             bd);
      gload16(bb + 64 * 2048, bd + 4096);
    }
    const char* ab = (const char*)As + cur * 8192;
    const char* bbk = (const char*)Bs + cur * 8192;
    s16x8 af[4], bf_[4];
    #pragma unroll
    for (int mf = 0; mf < 4; ++mf)
      af[mf] = *(const s16x8*)(ab + (wm * 64 + mf * 16 + c) * 64 + g * 16);
    #pragma unroll
    for (int nf = 0; nf < 4; ++nf)
      bf_[nf] = *(const s16x8*)(bbk + (wn * 64 + nf * 16 + c) * 64 + g * 16);
    #pragma unroll
    for (int mf = 0; mf < 4; ++mf)
      #pragma unroll
      for (int nf = 0; nf < 4; ++nf)
        acc[mf][nf] = MFMA16(af[mf], bf_[nf], acc[mf][nf]);
    __syncthreads();   // drains prefetch (vmcnt 0) + protects buffer reuse
  }

  // epilogue: m = m0+wm*64+mf*16+g*4+r ; n = n0+wn*64+nf*16+c
  #pragma unroll
  for (int mf = 0; mf < 4; ++mf) {
    #pragma unroll
    for (int nf = 0; nf < 4; ++nf) {
      const int mbase = m0 + wm * 64 + mf * 16 + g * 4;
      const int n = n0 + wn * 64 + nf * 16 + c;
      if (omode == 0) {
        u16* O = (u16*)outp;
        #pragma unroll
        for (int r = 0; r < 4; ++r) {
          const int m = mbase + r;
          const int b = m >> 10, sl = m & 1023, h = n >> 6, dk = n & 63;
          O[((size_t)(b * 16 + h) * 1024 + sl) * 64 + dk] = f2b(acc[mf][nf][r]);
        }
      } else if (omode == 1) {
        u16* O = (u16*)outp;
        ushort4 pk;
        pk.x = f2b(acc[mf][nf][0]);
        pk.y = f2b(acc[mf][nf][1]);
        pk.z = f2b(acc[mf][nf][2]);
        pk.w = f2b(acc[mf][nf][3]);
        const int b = mbase >> 10, sl = mbase & 1023, h = n >> 6, dk = n & 63;
        *(ushort4*)&O[((size_t)(b * 16 + h) * 64 + dk) * 1024 + sl] = pk;
      } else {
        float* O = (float*)outp;
        #pragma unroll
        for (int r = 0; r < 4; ++r)
          O[(size_t)(mbase + r) * 1024 + n] = acc[mf][nf][r];
      }
    }
  }
}

__global__ __launch_bounds__(256) void gemm_qkv(
    const u16* __restrict__ Xq, const u16* __restrict__ Xk, const u16* __restrict__ Xv,
    const u16* __restrict__ Wq2, const u16* __restrict__ Wk2, const u16* __restrict__ Wv2,
    const float* __restrict__ bq, const float* __restrict__ bk, const float* __restrict__ bv,
    u16* __restrict__ q2g, u16* __restrict__ k2g, u16* __restrict__ vTg)
{
  const int z = blockIdx.z;
  const u16* A    = z == 0 ? Xq  : (z == 1 ? Xk  : Xv);
  const u16* B2   = z == 0 ? Wq2 : (z == 1 ? Wk2 : Wv2);
  const float* bb = z == 0 ? bq  : (z == 1 ? bk  : bv);
  void* O         = z == 0 ? (void*)q2g : (z == 1 ? (void*)k2g : (void*)vTg);
  gemm_body(A, B2, bb, O, z == 2 ? 1 : 0);
}

__global__ __launch_bounds__(256) void gemm_out2(
    const u16* __restrict__ A, const u16* __restrict__ B2,
    const float* __restrict__ bias, float* __restrict__ out)
{
  gemm_body(A, B2, bias, out, 2);
}

// ---------------------------------------------------------------------------
// MFMA flash attention, rel-pos bias.  Block = (qt,h,b), 4 waves; wave w owns
// q-rows w*16..+15.  K/V tiles (64x64 u16 = 8 KB each) staged via
// global_load_lds with XOR chunk swizzle (linear LDS dest, inverse-swizzled
// per-lane SOURCE, swizzled READ: chunk j ^= row&7) -> frag ds_read_b128 is
// 2-way/free.  Double-buffered, 2-phase prefetch, one barrier per tile.
// ---------------------------------------------------------------------------
__global__ __launch_bounds__(256) void attn3(
    const u16* __restrict__ q2g, const u16* __restrict__ k2g,
    const u16* __restrict__ vTg, const float* __restrict__ rel,
    u16* __restrict__ ctx)
{
  __shared__ __attribute__((aligned(16))) u16 q_s[64][64];     // 8 KB
  __shared__ __attribute__((aligned(16))) u16 k_s[2][4096];    // 16 KB
  __shared__ __attribute__((aligned(16))) u16 v_s[2][4096];    // 16 KB
  __shared__ __attribute__((aligned(16))) u16 p_s[64][72];     // 9 KB
  __shared__ __attribute__((aligned(16))) float bias_s[64][34];// 8.7 KB

  const int tid = threadIdx.x;
  const int w = tid >> 6, lane = tid & 63;
  const int c = lane & 15, g = lane >> 4;
  const int qt = blockIdx.x, hd = blockIdx.y, b = blockIdx.z;
  const int l0 = qt * 64, bh = b * 16 + hd;

  const u16* kbase = k2g + (size_t)bh * (SEQ * DKH);   // [S][64]
  const u16* vbase = vTg + (size_t)bh * (DKH * SEQ);   // [64][S]

  // staging geometry: chunk D = i*256+tid -> (r = D>>3, jj = D&7);
  // source chunk j = jj ^ (r&7); i=1 is r+32 (same j since 32 % 8 == 0).
  const int r0 = tid >> 3;
  const int j0 = (tid & 7) ^ (r0 & 7);
  const u16* kP = kbase + (size_t)r0 * 64 + j0 * 8;     // + kt*4096 (+2048 for i=1)
  const u16* vP = vbase + (size_t)r0 * 1024 + j0 * 8;   // + kt*64   (+32768 for i=1)
  char* kD = (char*)k_s + w * 1024;                     // + buf*8192 + i*4096
  char* vD = (char*)v_s + w * 1024;

  // ---- one-time q stage (64x64) ----
  const u16* qsrc = q2g + ((size_t)bh * SEQ + l0) * 64;
  #pragma unroll
  for (int i = 0; i < 2; ++i) {
    const int f16 = tid * 2 + i;
    const int r = f16 >> 3, ch = (f16 & 7) * 8;
    *(uint4*)&q_s[r][ch] = *(const uint4*)&qsrc[r * 64 + ch];
  }
  // stage K/V tile 0 into buf 0 (async; drained by the next barrier)
  gload16(kP,         kD);
  gload16(kP + 2048,  kD + 4096);
  gload16(vP,         vD);
  gload16(vP + 32768, vD + 4096);
  __syncthreads();

  // ---- bias table: bias_s[r][j] = q_r . rel[j] ----
  for (int e = tid; e < 64 * NREL; e += 256) {
    const int r = e / NREL;
    const int j = e - r * NREL;
    float s = 0.f;
    #pragma unroll
    for (int d = 0; d < DKH; ++d)
      s += b2f(q_s[r][d]) * rel[j * 64 + d];
    bias_s[r][j] = s;
  }

  // ---- per-wave q fragments ----
  s16x8 qf[2];
  #pragma unroll
  for (int ks = 0; ks < 2; ++ks)
    qf[ks] = *(const s16x8*)&q_s[w * 16 + c][ks * 32 + g * 8];
  __syncthreads();                       // bias_s visible

  // swizzled read chunk offsets (bytes) for ks = 0,1:  ((ks*4+g) ^ (c&7))*16
  const int cj = c & 7;
  const int jx0 = ((0 + g) ^ cj) * 16;
  const int jx1 = ((4 + g) ^ cj) * 16;

  float mr[4], ls[4];
  f32x4 oacc[4];
  #pragma unroll
  for (int r = 0; r < 4; ++r) { mr[r] = -1e30f; ls[r] = 0.f; }
  #pragma unroll
  for (int fd = 0; fd < 4; ++fd) oacc[fd] = (f32x4){0.f, 0.f, 0.f, 0.f};

  const int qb = w * 16 + g * 4;

  for (int kt = 0; kt < SEQ / 64; ++kt) {
    const int cur = kt & 1;
    if (kt < SEQ / 64 - 1) {             // prefetch tile kt+1
      const size_t ko = (size_t)(kt + 1) * 4096;
      const size_t vo = (size_t)(kt + 1) * 64;
      char* kd = kD + (cur ^ 1) * 8192;
      char* vd = vD + (cur ^ 1) * 8192;
      gload16(kP + ko,         kd);
      gload16(kP + ko + 2048,  kd + 4096);
      gload16(vP + vo,         vd);
      gload16(vP + vo + 32768, vd + 4096);
    }

    // ---- scores: QK^T from swizzled K tile ----
    const char* kb = (const char*)k_s + cur * 8192;
    f32x4 sc[4];
    #pragma unroll
    for (int f = 0; f < 4; ++f) {
      const int rb = (f * 16 + c) * 128;
      const s16x8 kf0 = *(const s16x8*)(kb + rb + jx0);
      const s16x8 kf1 = *(const s16x8*)(kb + rb + jx1);
      sc[f] = (f32x4){0.f, 0.f, 0.f, 0.f};
      sc[f] = MFMA16(qf[0], kf0, sc[f]);
      sc[f] = MFMA16(qf[1], kf1, sc[f]);
    }

    // ---- bias + online softmax (row = qb+r, 16 c-lanes per row) ----
    #pragma unroll
    for (int r = 0; r < 4; ++r) {
      const int rowg = l0 + qb + r;
      float sv[4], vmax = -1e30f;
      #pragma unroll
      for (int f = 0; f < 4; ++f) {
        const int colg = kt * 64 + f * 16 + c;
        int dd = colg - rowg;
        dd = (dd < -16 ? -16 : (dd > 16 ? 16 : dd)) + 16;
        sv[f] = sc[f][r] * 0.125f + bias_s[qb + r][dd];
        vmax = fmaxf(vmax, sv[f]);
      }
      #pragma unroll
      for (int off = 1; off < 16; off <<= 1) vmax = fmaxf(vmax, __shfl_xor(vmax, off, 64));
      const float mnew = fmaxf(mr[r], vmax);
      const float sf = __expf(mr[r] - mnew);
      float psum = 0.f;
      #pragma unroll
      for (int f = 0; f < 4; ++f) { sv[f] = __expf(sv[f] - mnew); psum += sv[f]; }
      #pragma unroll
      for (int off = 1; off < 16; off <<= 1) psum += __shfl_xor(psum, off, 64);
      mr[r] = mnew;
      ls[r] = ls[r] * sf + psum;
      #pragma unroll
      for (int fd = 0; fd < 4; ++fd) oacc[fd][r] *= sf;
      #pragma unroll
      for (int f = 0; f < 4; ++f) p_s[qb + r][f * 16 + c] = f2b(sv[f]);
    }

    // ---- P.V: wave-private p_s + swizzled V tile ----
    const char* vb = (const char*)v_s + cur * 8192;
    #pragma unroll
    for (int ks = 0; ks < 2; ++ks) {
      const s16x8 pa = *(const s16x8*)&p_s[w * 16 + c][ks * 32 + g * 8];
      const int jx = ks ? jx1 : jx0;
      #pragma unroll
      for (int fd = 0; fd < 4; ++fd) {
        const s16x8 vv = *(const s16x8*)(vb + (fd * 16 + c) * 128 + jx);
        oacc[fd] = MFMA16(pa, vv, oacc[fd]);
      }
    }
    __syncthreads();   // drains prefetch + protects buffer/p_s reuse
  }

  // ---- normalize, write ctx bf16 [4096][1024] ----
  #pragma unroll
  for (int r = 0; r < 4; ++r) {
    const float inv = 1.0f / ls[r];
    const int row = l0 + w * 16 + g * 4 + r;
    #pragma unroll
    for (int fd = 0; fd < 4; ++fd)
      ctx[((size_t)b * 1024 + row) * 1024 + hd * 64 + fd * 16 + c] = f2b(oacc[fd][r] * inv);
  }
}

// ---------------------------------------------------------------------------
extern "C" void kernel_launch(void* const* d_in, const int* in_sizes, int n_in,
                              void* d_out, int out_size, void* d_ws, size_t ws_size,
                              hipStream_t stream)
{
  (void)in_sizes; (void)n_in; (void)out_size; (void)ws_size;
  const float* Q   = (const float*)d_in[0];
  const float* K   = (const float*)d_in[1];
  const float* V   = (const float*)d_in[2];
  const float* Wq  = (const float*)d_in[3];
  const float* bq  = (const float*)d_in[4];
  const float* Wk  = (const float*)d_in[5];
  const float* bk  = (const float*)d_in[6];
  const float* Wv  = (const float*)d_in[7];
  const float* bv  = (const float*)d_in[8];
  const float* Wo  = (const float*)d_in[9];
  const float* bo  = (const float*)d_in[10];
  const float* rel = (const float*)d_in[11];
  float* out = (float*)d_out;

  // ws map (bytes), peak 62,914,560:
  //   Xq 0 | Xk 8.39M | Xv 16.78M | W2q 25.17M | W2k 29.36M | W2v 33.55M
  //   | q2g 37.75M | k2g 46.14M | vTg 54.53M
  // ctx reuses Xq after QKV GEMM; W2o reuses Xk after QKV GEMM.
  char* ws = (char*)d_ws;
  u16* Xq  = (u16*)(ws);
  u16* Xk  = (u16*)(ws + 8388608);
  u16* Xv  = (u16*)(ws + 16777216);
  u16* W2q = (u16*)(ws + 25165824);
  u16* W2k = (u16*)(ws + 29360128);
  u16* W2v = (u16*)(ws + 33554432);
  u16* q2g = (u16*)(ws + 37748736);
  u16* k2g = (u16*)(ws + 46137344);
  u16* vTg = (u16*)(ws + 54525952);
  u16* ctx = Xq;
  u16* W2o = Xk;

  const dim3 blk(256);
  conv_x<<<2048, blk, 0, stream>>>(Q, Xq);
  conv_x<<<2048, blk, 0, stream>>>(K, Xk);
  conv_x<<<2048, blk, 0, stream>>>(V, Xv);
  conv_w<<<512, blk, 0, stream>>>(Wq, W2q);
  conv_w<<<512, blk, 0, stream>>>(Wk, W2k);
  conv_w<<<512, blk, 0, stream>>>(Wv, W2v);

  gemm_qkv<<<dim3(32, 8, 3), blk, 0, stream>>>(Xq, Xk, Xv, W2q, W2k, W2v,
                                               bq, bk, bv, q2g, k2g, vTg);

  attn3<<<dim3(SEQ / 64, NHEADS, BATCH), blk, 0, stream>>>(q2g, k2g, vTg, rel, ctx);

  conv_w<<<512, blk, 0, stream>>>(Wo, W2o);
  gemm_out2<<<dim3(32, 8), blk, 0, stream>>>(ctx, W2o, bo, out);
}